// Round 1
// baseline (114.335 us; speedup 1.0000x reference)
//
#include <hip/hip_runtime.h>
#include <hip/hip_bf16.h>

// Problem constants
#define P_ROWS   1024
#define N_IN     784
#define N_OUT    128
#define M_ROWS   785          // N_IN + 1 (bias row)
#define OUT_ELEMS (P_ROWS * N_OUT)   // 131072

// Device/group constants
#define V_REF_C  0.25f
// c0 ratio = G_MIN/(G_MAX-G_MIN), computed in double then truncated
// G_MIN = 1/983.3, G_MAX = 1/281.3
#define RATIO_F  ((float)((1.0/983.3) / ((1.0/281.3) - (1.0/983.3))))

// Workspace layout (bytes)
#define WS_MAX_OFF   0
#define AL_OFF       256
#define AL_BYTES     (M_ROWS * N_OUT * 16)            // 785*128 float4 = 1,607,680
#define PART_OFF     (AL_OFF + AL_BYTES)              // 1,607,936
#define NCH          4
// partials: NCH * 131072 floats = 2 MB.  total ws use ~3.7 MB

__global__ void init_ws(unsigned* wsmax) {
    if (threadIdx.x == 0) *wsmax = 0u;
}

// Global max |weight| over w_pos, w_neg, b_pos, b_neg -> atomicMax (uint bits,
// valid since all values are non-negative floats after fabsf).
__global__ void max_reduce(const float* __restrict__ wp, const float* __restrict__ wn,
                           const float* __restrict__ bp, const float* __restrict__ bn,
                           unsigned* wsmax) {
    const int nW = N_IN * N_OUT;   // 100352
    int gid = blockIdx.x * blockDim.x + threadIdx.x;
    int stride = gridDim.x * blockDim.x;
    float v = 0.0f;
    for (int i = gid; i < nW; i += stride)
        v = fmaxf(v, fmaxf(fabsf(wp[i]), fabsf(wn[i])));
    if (gid < N_OUT)
        v = fmaxf(v, fmaxf(fabsf(bp[gid]), fabsf(bn[gid])));
    // wave64 reduce
    for (int off = 32; off > 0; off >>= 1)
        v = fmaxf(v, __shfl_down(v, off, 64));
    __shared__ float smax[4];
    if ((threadIdx.x & 63) == 0) smax[threadIdx.x >> 6] = v;
    __syncthreads();
    if (threadIdx.x == 0) {
        v = fmaxf(fmaxf(smax[0], smax[1]), fmaxf(smax[2], smax[3]));
        atomicMax(wsmax, __float_as_uint(v));
    }
}

// Precompute per-(m,k): {A_pos, L_pos, A_neg, L_neg}
//   A = c0 + 0.5*w   (affine fold of scale * V_REF * G)
//   L = log2(n_param)
__global__ void precompute_al(const float* __restrict__ wp, const float* __restrict__ wn,
                              const float* __restrict__ bp, const float* __restrict__ bn,
                              const float* __restrict__ np, const unsigned* __restrict__ wsmax,
                              float4* __restrict__ AL) {
    int idx = blockIdx.x * blockDim.x + threadIdx.x;
    if (idx >= M_ROWS * N_OUT) return;
    int m = idx >> 7;          // / 128
    int k = idx & 127;
    float maxw = __uint_as_float(*wsmax);
    float c0 = maxw * 0.5f * RATIO_F;
    float wpos = (m < N_IN) ? wp[m * N_OUT + k] : bp[k];
    float wneg = (m < N_IN) ? wn[m * N_OUT + k] : bn[k];
    float npos = np[m * (2 * N_OUT) + 2 * k];
    float nneg = np[m * (2 * N_OUT) + 2 * k + 1];
    float4 al;
    al.x = c0 + 0.5f * wpos;
    al.y = __builtin_amdgcn_logf(npos);   // v_log_f32 = log2
    al.z = c0 + 0.5f * wneg;
    al.w = __builtin_amdgcn_logf(nneg);
    AL[idx] = al;
}

// Main kernel: grid = 128 p-tiles * NCH m-chunks = 512 blocks, 256 threads.
// Thread t: k = t&127, pg = t>>7; accumulates 4 p-rows (p0 + pg*4 + 0..3).
// e[p,m] staged in LDS (computed from x on the fly).
#define ELDS_STRIDE 200
__global__ __launch_bounds__(256) void memristor_main(const float* __restrict__ x,
                                                      const float4* __restrict__ AL,
                                                      float* __restrict__ part) {
    const int b   = blockIdx.x;
    const int ch  = b & (NCH - 1);
    const int pt  = b >> 2;
    const int p0  = pt * 8;
    const int m0  = ch * 196;
    const int cnt = (ch == NCH - 1) ? (M_ROWS - 3 * 196) : 196;   // 196,196,196,197

    __shared__ float e_lds[8 * ELDS_STRIDE];
    const int tid = threadIdx.x;

    // stage e = log2(2x) (bias row -> log2(2) = 1), sentinel for x == 0
    for (int pi = 0; pi < 8; ++pi) {
        const int row = p0 + pi;
        for (int j = tid; j < cnt; j += 256) {
            int m = m0 + j;
            float xv = (m < N_IN) ? x[row * N_IN + m] : 1.0f;
            float e = (xv > 0.0f) ? __builtin_amdgcn_logf(2.0f * xv) : -1.0e4f;
            e_lds[pi * ELDS_STRIDE + j] = e;
        }
    }
    __syncthreads();

    const int k  = tid & 127;
    const int pg = tid >> 7;
    const float* eb = e_lds + pg * 4 * ELDS_STRIDE;
    const float4* ALp = AL + (size_t)m0 * N_OUT + k;

    float a0 = 0.0f, a1 = 0.0f, a2 = 0.0f, a3 = 0.0f;
    #pragma unroll 2
    for (int j = 0; j < cnt; ++j) {
        float4 al = ALp[(size_t)j * N_OUT];
        float e0 = eb[j];
        float e1 = eb[ELDS_STRIDE + j];
        float e2 = eb[2 * ELDS_STRIDE + j];
        float e3 = eb[3 * ELDS_STRIDE + j];
        a0 += al.x * __builtin_amdgcn_exp2f(e0 * al.y) - al.z * __builtin_amdgcn_exp2f(e0 * al.w);
        a1 += al.x * __builtin_amdgcn_exp2f(e1 * al.y) - al.z * __builtin_amdgcn_exp2f(e1 * al.w);
        a2 += al.x * __builtin_amdgcn_exp2f(e2 * al.y) - al.z * __builtin_amdgcn_exp2f(e2 * al.w);
        a3 += al.x * __builtin_amdgcn_exp2f(e3 * al.y) - al.z * __builtin_amdgcn_exp2f(e3 * al.w);
    }

    float* o = part + (size_t)ch * OUT_ELEMS + (size_t)(p0 + pg * 4) * N_OUT + k;
    o[0 * N_OUT] = a0;
    o[1 * N_OUT] = a1;
    o[2 * N_OUT] = a2;
    o[3 * N_OUT] = a3;
}

__global__ void combine(const float* __restrict__ part, float* __restrict__ out) {
    int i = blockIdx.x * blockDim.x + threadIdx.x;
    if (i >= OUT_ELEMS) return;
    out[i] = (part[i] + part[OUT_ELEMS + i]) +
             (part[2 * OUT_ELEMS + i] + part[3 * OUT_ELEMS + i]);
}

extern "C" void kernel_launch(void* const* d_in, const int* in_sizes, int n_in,
                              void* d_out, int out_size, void* d_ws, size_t ws_size,
                              hipStream_t stream) {
    const float* x  = (const float*)d_in[0];
    const float* wp = (const float*)d_in[1];
    const float* wn = (const float*)d_in[2];
    const float* bp = (const float*)d_in[3];
    const float* bn = (const float*)d_in[4];
    const float* np = (const float*)d_in[5];
    float* out = (float*)d_out;

    unsigned* wsmax = (unsigned*)((char*)d_ws + WS_MAX_OFF);
    float4*   AL    = (float4*)((char*)d_ws + AL_OFF);
    float*    part  = (float*)((char*)d_ws + PART_OFF);

    init_ws<<<1, 64, 0, stream>>>(wsmax);
    max_reduce<<<128, 256, 0, stream>>>(wp, wn, bp, bn, wsmax);
    precompute_al<<<(M_ROWS * N_OUT + 255) / 256, 256, 0, stream>>>(wp, wn, bp, bn, np, wsmax, AL);
    memristor_main<<<128 * NCH, 256, 0, stream>>>(x, AL, part);
    combine<<<(OUT_ELEMS + 255) / 256, 256, 0, stream>>>(part, out);
}

// Round 2
// 100.108 us; speedup vs baseline: 1.1421x; 1.1421x over previous
//
#include <hip/hip_runtime.h>
#include <hip/hip_bf16.h>

// Problem constants
#define P_ROWS   1024
#define N_IN     784
#define N_OUT    128
#define M_ROWS   785          // N_IN + 1 (bias row)
#define OUT_ELEMS (P_ROWS * N_OUT)   // 131072

// c0 ratio = G_MIN/(G_MAX-G_MIN) = 281.3/(983.3-281.3)
#define RATIO_F  ((float)((1.0/983.3) / ((1.0/281.3) - (1.0/983.3))))

// m-chunking: 8 chunks of 98 (last = 99) -> chunk id == blockIdx%8 == XCD id
#define CH_N     8
#define CH_BASE  98
#define CH_LAST  (M_ROWS - (CH_N - 1) * CH_BASE)   // 99

// Workspace layout (bytes)
#define WS_MAX_OFF   0
#define AL_OFF       256
#define AL_BYTES     (M_ROWS * N_OUT * 16)   // 785*128 float4 = 1.6 MB

// ---------------------------------------------------------------------------
// K1: global max|w| via per-block reduce + atomicMax on uint bits (ws pre-zeroed
// by hipMemsetAsync; all values nonneg after fabsf so uint compare == float).
__global__ __launch_bounds__(256) void max_reduce(
        const float* __restrict__ wp, const float* __restrict__ wn,
        const float* __restrict__ bp, const float* __restrict__ bn,
        unsigned* __restrict__ wsmax) {
    const int nW = N_IN * N_OUT;   // 100352
    int gid = blockIdx.x * blockDim.x + threadIdx.x;
    int stride = gridDim.x * blockDim.x;
    float v = 0.0f;
    for (int i = gid; i < nW; i += stride)
        v = fmaxf(v, fmaxf(fabsf(wp[i]), fabsf(wn[i])));
    if (gid < N_OUT)
        v = fmaxf(v, fmaxf(fabsf(bp[gid]), fabsf(bn[gid])));
    for (int off = 32; off > 0; off >>= 1)
        v = fmaxf(v, __shfl_down(v, off, 64));
    __shared__ float smax[4];
    if ((threadIdx.x & 63) == 0) smax[threadIdx.x >> 6] = v;
    __syncthreads();
    if (threadIdx.x == 0) {
        v = fmaxf(fmaxf(smax[0], smax[1]), fmaxf(smax[2], smax[3]));
        atomicMax(wsmax, __float_as_uint(v));
    }
}

// ---------------------------------------------------------------------------
// K2: per-(m,k) params {A_pos, log2(n_pos), A_neg, log2(n_neg)},
//     A = c0 + 0.5*w  (affine fold of final scale * V_REF * G)
__global__ __launch_bounds__(256) void precompute_al(
        const float* __restrict__ wp, const float* __restrict__ wn,
        const float* __restrict__ bp, const float* __restrict__ bn,
        const float* __restrict__ np, const unsigned* __restrict__ wsmax,
        float4* __restrict__ AL) {
    int idx = blockIdx.x * blockDim.x + threadIdx.x;
    if (idx >= M_ROWS * N_OUT) return;
    int m = idx >> 7;
    int k = idx & 127;
    float maxw = __uint_as_float(*wsmax);
    float c0 = maxw * 0.5f * RATIO_F;
    float wpos = (m < N_IN) ? wp[m * N_OUT + k] : bp[k];
    float wneg = (m < N_IN) ? wn[m * N_OUT + k] : bn[k];
    float npos = np[m * (2 * N_OUT) + 2 * k];
    float nneg = np[m * (2 * N_OUT) + 2 * k + 1];
    float4 al;
    al.x = c0 + 0.5f * wpos;
    al.y = __builtin_amdgcn_logf(npos);
    al.z = c0 + 0.5f * wneg;
    al.w = __builtin_amdgcn_logf(nneg);
    AL[idx] = al;
}

// ---------------------------------------------------------------------------
// K3: main. grid = 256 p-tiles (4 rows each) x 8 m-chunks = 2048 blocks.
// blockIdx = pt*8 + ch  -> ch == XCD id (round-robin dispatch), so each AL
// chunk (~200 KB) stays hot in one XCD's L2.
// 256 threads: k = t&127, pg = t>>7; thread accumulates rows p0+2pg, p0+2pg+1.
// Results atomically added into out (pre-zeroed by memset); 8 adds/output.
__global__ __launch_bounds__(256) void memristor_main(
        const float* __restrict__ x, const float4* __restrict__ AL,
        float* __restrict__ out) {
    const int b   = blockIdx.x;
    const int ch  = b & (CH_N - 1);
    const int pt  = b >> 3;
    const int p0  = pt * 4;
    const int m0  = ch * CH_BASE;
    const int cnt = (ch == CH_N - 1) ? CH_LAST : CH_BASE;

    __shared__ float e_lds[CH_LAST * 4];   // [j][row 0..3], 1.6 KB
    const int tid = threadIdx.x;

    // stage e = log2(2x) (bias row m==784 -> 1.0), sentinel for x == 0
    if (tid < cnt) {
        const int m = m0 + tid;
        float4 e4;
        if (m < N_IN) {
            float x0 = x[(p0 + 0) * N_IN + m];
            float x1 = x[(p0 + 1) * N_IN + m];
            float x2 = x[(p0 + 2) * N_IN + m];
            float x3 = x[(p0 + 3) * N_IN + m];
            e4.x = (x0 > 0.0f) ? __builtin_amdgcn_logf(2.0f * x0) : -1.0e4f;
            e4.y = (x1 > 0.0f) ? __builtin_amdgcn_logf(2.0f * x1) : -1.0e4f;
            e4.z = (x2 > 0.0f) ? __builtin_amdgcn_logf(2.0f * x2) : -1.0e4f;
            e4.w = (x3 > 0.0f) ? __builtin_amdgcn_logf(2.0f * x3) : -1.0e4f;
        } else {
            e4.x = e4.y = e4.z = e4.w = 1.0f;
        }
        ((float4*)e_lds)[tid] = e4;
    }
    __syncthreads();

    const int k  = tid & 127;
    const int pg = tid >> 7;
    // float2 pairs: row-pair pg of column j at (float2*)e_lds + j*2 + pg
    const float2* __restrict__ e2 = (const float2*)e_lds + pg;
    const float4* __restrict__ ALp = AL + (size_t)m0 * N_OUT + k;

    float a0 = 0.0f, a1 = 0.0f;
    #pragma unroll 4
    for (int j = 0; j < cnt; ++j) {
        float4 al = ALp[(size_t)j * N_OUT];
        float2 e  = e2[2 * j];            // broadcast within wave
        float Ep0 = __builtin_amdgcn_exp2f(e.x * al.y);
        float En0 = __builtin_amdgcn_exp2f(e.x * al.w);
        float Ep1 = __builtin_amdgcn_exp2f(e.y * al.y);
        float En1 = __builtin_amdgcn_exp2f(e.y * al.w);
        a0 = fmaf(al.x, Ep0, a0);
        a0 = fmaf(-al.z, En0, a0);
        a1 = fmaf(al.x, Ep1, a1);
        a1 = fmaf(-al.z, En1, a1);
    }

    float* o = out + (size_t)(p0 + pg * 2) * N_OUT + k;
    unsafeAtomicAdd(o, a0);
    unsafeAtomicAdd(o + N_OUT, a1);
}

// ---------------------------------------------------------------------------
extern "C" void kernel_launch(void* const* d_in, const int* in_sizes, int n_in,
                              void* d_out, int out_size, void* d_ws, size_t ws_size,
                              hipStream_t stream) {
    const float* x  = (const float*)d_in[0];
    const float* wp = (const float*)d_in[1];
    const float* wn = (const float*)d_in[2];
    const float* bp = (const float*)d_in[3];
    const float* bn = (const float*)d_in[4];
    const float* np = (const float*)d_in[5];
    float* out = (float*)d_out;

    unsigned* wsmax = (unsigned*)((char*)d_ws + WS_MAX_OFF);
    float4*   AL    = (float4*)((char*)d_ws + AL_OFF);

    hipMemsetAsync(wsmax, 0, sizeof(unsigned), stream);
    hipMemsetAsync(out, 0, (size_t)OUT_ELEMS * sizeof(float), stream);
    max_reduce<<<64, 256, 0, stream>>>(wp, wn, bp, bn, wsmax);
    precompute_al<<<(M_ROWS * N_OUT + 255) / 256, 256, 0, stream>>>(wp, wn, bp, bn, np, wsmax, AL);
    memristor_main<<<256 * CH_N, 256, 0, stream>>>(x, AL, out);
}